// Round 4
// baseline (280.251 us; speedup 1.0000x reference)
//
#include <hip/hip_runtime.h>

#define DEV __device__ __forceinline__

typedef __attribute__((ext_vector_type(8))) short short8;
typedef __attribute__((ext_vector_type(4))) float floatx4;
typedef __attribute__((ext_vector_type(2))) unsigned int uint2v;
typedef unsigned short u16;

// round-to-nearest-even fp32 -> bf16 (bit pattern)
DEV u16 f2bf(float f) {
  unsigned int u = __float_as_uint(f);
  u += 0x7fffu + ((u >> 16) & 1u);
  return (u16)(u >> 16);
}

// pack two fp32 -> 2 bf16 in one u32 (a -> lo, b -> hi), single instruction, RNE
DEV unsigned int cvtpk(float a, float b) {
  unsigned int r;
  asm("v_cvt_pk_bf16_f32 %0, %1, %2" : "=v"(r) : "v"(a), "v"(b));
  return r;
}

// async global->LDS, 16B/lane; LDS dest = wave-uniform base + lane*16
DEV void load16_to_lds(const void* g, void* l) {
  __builtin_amdgcn_global_load_lds(
      (const __attribute__((address_space(1))) unsigned int*)g,
      (__attribute__((address_space(3))) unsigned int*)l, 16, 0, 0);
}

// XCD chunk-swizzle (T1). Requires nwg % 8 == 0 (bijective).
DEV int xcd_swz(int flat, int nwg) {
  return (flat & 7) * (nwg >> 3) + (flat >> 3);
}

#define MFMA16(A, B, C) __builtin_amdgcn_mfma_f32_16x16x32_bf16(A, B, C, 0, 0, 0)
#define EXP2(x) __builtin_amdgcn_exp2f(x)  // raw v_exp_f32; args bounded ~|12|

// Problem constants: B=2, T=S=2048, E=1024, H=16, DH=64
// Q pre-scale: (1/8) * log2(e) so softmax uses exp2 directly.
#define QSCALE 0.18033688011112042f

// ---------------------------------------------------------------------------
// Swizzled 16-row x 32-k LDS blocks (1 KB). Global chunk g (16B) of row r
// lives at slot r*4 + ((g + (r>>2)) & 3). 2-way residue -> conflict-free.
DEV void stage_block(const u16* src_row0, int k0, int ln, void* ldsbase) {
  int r = ln >> 2;
  int p = ((ln & 3) - (ln >> 4)) & 3;
  load16_to_lds((const char*)(src_row0 + (size_t)r * 1024 + k0) + p * 16, ldsbase);
}
DEV const short8* frag_addr(const u16* base, int blk, int c, int q) {
  int slot = c * 4 + ((q + (c >> 2)) & 3);
  return (const short8*)(base + blk * 512 + slot * 8);
}

// ---------------------------------------------------------------------------
// K0: fp32->bf16 of 4 weight matrices (1M el each) + 3 activations (4M el each)
__global__ __launch_bounds__(256) void cvt_all(
    const float* __restrict__ w0, const float* __restrict__ w1,
    const float* __restrict__ w2, const float* __restrict__ w3,
    const float* __restrict__ a0, const float* __restrict__ a1, const float* __restrict__ a2,
    u16* __restrict__ e0, u16* __restrict__ e1, u16* __restrict__ e2, u16* __restrict__ e3,
    u16* __restrict__ f0, u16* __restrict__ f1, u16* __restrict__ f2) {
  const int t = blockIdx.y;
  const float* s;
  u16* d;
  size_t base;
  if (t < 4) {
    s = t == 0 ? w0 : t == 1 ? w1 : t == 2 ? w2 : w3;
    d = t == 0 ? e0 : t == 1 ? e1 : t == 2 ? e2 : e3;
    base = 0;
  } else {
    int a = (t - 4) >> 2;
    s = a == 0 ? a0 : a == 1 ? a1 : a2;
    d = a == 0 ? f0 : a == 1 ? f1 : f2;
    base = (size_t)((t - 4) & 3) * 1048576;
  }
  size_t i = base + (size_t)(blockIdx.x * 256 + threadIdx.x) * 4;
  float4 v = *(const float4*)(s + i);
  ushort4 o;
  o.x = f2bf(v.x); o.y = f2bf(v.y); o.z = f2bf(v.z); o.w = f2bf(v.w);
  *(ushort4*)(d + i) = o;
}

// ---------------------------------------------------------------------------
// QKV projection GEMM, pure bf16, 256x128 tile, BK=32, 8 waves (4x2 of 64x64).
// Double-buffered LDS, one barrier per K-step. grid (8, 16, 3): bx is the
// n-panel for z<=1 -> natural %8 XCD round-robin pins one 0.25MB B-panel per
// XCD (L2-resident) while the A-stream walks m sequentially.
__global__ __launch_bounds__(512, 4) void qkv_gemm(
    const u16* __restrict__ qb, const u16* __restrict__ kb, const u16* __restrict__ vb,
    const u16* __restrict__ wq, const u16* __restrict__ wk, const u16* __restrict__ wv,
    const float* __restrict__ bq, const float* __restrict__ bk, const float* __restrict__ bv,
    u16* __restrict__ Qh, u16* __restrict__ Kh, u16* __restrict__ VT) {
  __shared__ __align__(16) u16 As[2][8192];  // 16 x 1KB row-blocks
  __shared__ __align__(16) u16 Bs[2][4096];  // 8 x 1KB row-blocks
  const int tid = threadIdx.x;
  const int w = tid >> 6, ln = tid & 63, q = ln >> 4, c = ln & 15;
  const int wr = w >> 1, wc = w & 1;  // 4x2 wave grid, 64x64 each
  const int z = blockIdx.z;
  int m_idx, n_idx;
  if (z == 2) {  // A=wv (M=1024), B=vb (N=4096)
    int f2 = blockIdx.x + 8 * blockIdx.y;  // 0..127
    n_idx = f2 & 31;
    m_idx = f2 >> 5;
  } else {  // A=activations (M=4096), B=weights (N=1024)
    n_idx = blockIdx.x;
    m_idx = blockIdx.y;
  }
  const int m0 = m_idx * 256, n0 = n_idx * 128;
  const u16* Asrc = z == 0 ? qb : (z == 1 ? kb : wv);
  const u16* Bsrc = z == 0 ? wq : (z == 1 ? wk : vb);

  floatx4 acc[4][4];
#pragma unroll
  for (int i = 0; i < 4; ++i)
#pragma unroll
    for (int j = 0; j < 4; ++j) acc[i][j] = (floatx4){0.f, 0.f, 0.f, 0.f};

  // 24 x 1KB stage blocks per K-step (A:16, B:8); wave w does idx = w*3+j.
#pragma unroll
  for (int j = 0; j < 3; ++j) {
    int idx = w * 3 + j;
    if (idx < 16)
      stage_block(Asrc + (size_t)(m0 + idx * 16) * 1024, 0, ln, (char*)As[0] + idx * 1024);
    else
      stage_block(Bsrc + (size_t)(n0 + (idx - 16) * 16) * 1024, 0, ln, (char*)Bs[0] + (idx - 16) * 1024);
  }

  int cur = 0;
  for (int k0 = 0; k0 < 1024; k0 += 32) {
    __syncthreads();  // drains vmcnt -> buf[cur] staged; all waves done reading buf[cur^1]
    if (k0 + 32 < 1024) {
      const int nb = cur ^ 1;
#pragma unroll
      for (int j = 0; j < 3; ++j) {
        int idx = w * 3 + j;
        if (idx < 16)
          stage_block(Asrc + (size_t)(m0 + idx * 16) * 1024, k0 + 32, ln, (char*)As[nb] + idx * 1024);
        else
          stage_block(Bsrc + (size_t)(n0 + (idx - 16) * 16) * 1024, k0 + 32, ln,
                      (char*)Bs[nb] + (idx - 16) * 1024);
      }
    }
    short8 a[4], bb[4];
#pragma unroll
    for (int mt = 0; mt < 4; ++mt) a[mt] = *frag_addr(As[cur], wr * 4 + mt, c, q);
#pragma unroll
    for (int nt = 0; nt < 4; ++nt) bb[nt] = *frag_addr(Bs[cur], wc * 4 + nt, c, q);
    __builtin_amdgcn_s_setprio(1);
#pragma unroll
    for (int mt = 0; mt < 4; ++mt)
#pragma unroll
      for (int nt = 0; nt < 4; ++nt) acc[mt][nt] = MFMA16(a[mt], bb[nt], acc[mt][nt]);
    __builtin_amdgcn_s_setprio(0);
    cur ^= 1;
  }

  if (z <= 1) {
    const float* bias = z ? bk : bq;
    u16* dst = z ? Kh : Qh;
    const float scale = z ? 1.0f : QSCALE;
    float bn[4];
#pragma unroll
    for (int nt = 0; nt < 4; ++nt) bn[nt] = bias[n0 + wc * 64 + nt * 16 + c];
#pragma unroll
    for (int mt = 0; mt < 4; ++mt)
#pragma unroll
      for (int r = 0; r < 4; ++r) {
        int m = m0 + wr * 64 + mt * 16 + 4 * q + r;
        int bbv = m >> 11, t = m & 2047;
#pragma unroll
        for (int nt = 0; nt < 4; ++nt) {
          int n = n0 + wc * 64 + nt * 16 + c;
          dst[((size_t)(bbv * 16 + (n >> 6)) * 2048 + t) * 64 + (n & 63)] =
              f2bf((acc[mt][nt][r] + bn[nt]) * scale);
        }
      }
  } else {
    float bm[4][4];
#pragma unroll
    for (int mt = 0; mt < 4; ++mt)
#pragma unroll
      for (int r = 0; r < 4; ++r) bm[mt][r] = bv[m0 + wr * 64 + mt * 16 + 4 * q + r];
#pragma unroll
    for (int mt = 0; mt < 4; ++mt)
#pragma unroll
      for (int r = 0; r < 4; ++r) {
        int d = m0 + wr * 64 + mt * 16 + 4 * q + r;
        int hh = d >> 6, dl = d & 63;
#pragma unroll
        for (int nt = 0; nt < 4; ++nt) {
          int s = n0 + wc * 64 + nt * 16 + c;
          int bbv = s >> 11, sl = s & 2047;
          VT[((size_t)(bbv * 16 + hh) * 64 + dl) * 2048 + sl] = f2bf(acc[mt][nt][r] + bm[mt][r]);
        }
      }
  }
}

// ---------------------------------------------------------------------------
// Output projection: out[4096,1024] = A_bf16 @ Wo^T + bo (fp32).
// 256x128 tile, 8 waves, double-buffered, grid (8, 16).
__global__ __launch_bounds__(512, 4) void oproj_gemm(const u16* __restrict__ Ap, const u16* __restrict__ Wp,
                                                     const float* __restrict__ bias, float* __restrict__ out) {
  __shared__ __align__(16) u16 As[2][8192];
  __shared__ __align__(16) u16 Bs[2][4096];
  const int tid = threadIdx.x;
  const int w = tid >> 6, ln = tid & 63, q = ln >> 4, c = ln & 15;
  const int wr = w >> 1, wc = w & 1;
  const int n0 = blockIdx.x * 128, m0 = blockIdx.y * 256;

  floatx4 acc[4][4];
#pragma unroll
  for (int i = 0; i < 4; ++i)
#pragma unroll
    for (int j = 0; j < 4; ++j) acc[i][j] = (floatx4){0.f, 0.f, 0.f, 0.f};

#pragma unroll
  for (int j = 0; j < 3; ++j) {
    int idx = w * 3 + j;
    if (idx < 16)
      stage_block(Ap + (size_t)(m0 + idx * 16) * 1024, 0, ln, (char*)As[0] + idx * 1024);
    else
      stage_block(Wp + (size_t)(n0 + (idx - 16) * 16) * 1024, 0, ln, (char*)Bs[0] + (idx - 16) * 1024);
  }

  int cur = 0;
  for (int k0 = 0; k0 < 1024; k0 += 32) {
    __syncthreads();
    if (k0 + 32 < 1024) {
      const int nb = cur ^ 1;
#pragma unroll
      for (int j = 0; j < 3; ++j) {
        int idx = w * 3 + j;
        if (idx < 16)
          stage_block(Ap + (size_t)(m0 + idx * 16) * 1024, k0 + 32, ln, (char*)As[nb] + idx * 1024);
        else
          stage_block(Wp + (size_t)(n0 + (idx - 16) * 16) * 1024, k0 + 32, ln,
                      (char*)Bs[nb] + (idx - 16) * 1024);
      }
    }
    short8 a[4], bb[4];
#pragma unroll
    for (int mt = 0; mt < 4; ++mt) a[mt] = *frag_addr(As[cur], wr * 4 + mt, c, q);
#pragma unroll
    for (int nt = 0; nt < 4; ++nt) bb[nt] = *frag_addr(Bs[cur], wc * 4 + nt, c, q);
    __builtin_amdgcn_s_setprio(1);
#pragma unroll
    for (int mt = 0; mt < 4; ++mt)
#pragma unroll
      for (int nt = 0; nt < 4; ++nt) acc[mt][nt] = MFMA16(a[mt], bb[nt], acc[mt][nt]);
    __builtin_amdgcn_s_setprio(0);
    cur ^= 1;
  }

  float bn[4];
#pragma unroll
  for (int nt = 0; nt < 4; ++nt) bn[nt] = bias[n0 + wc * 64 + nt * 16 + c];
#pragma unroll
  for (int mt = 0; mt < 4; ++mt)
#pragma unroll
    for (int r = 0; r < 4; ++r) {
      int m = m0 + wr * 64 + mt * 16 + 4 * q + r;
#pragma unroll
      for (int nt = 0; nt < 4; ++nt)
        out[(size_t)m * 1024 + n0 + wc * 64 + nt * 16 + c] = acc[mt][nt][r] + bn[nt];
    }
}

// ---------------------------------------------------------------------------
// K2: flash attention, S^T form, t-tile 128 (16 t per wave, 8 waves).
// Double-buffered K/V staging, one barrier per s-tile, XCD chunk-swizzled.
// grid (T/128, H, B) = (16,16,2), 512 threads. LDS 50 KB -> 2 blocks/CU.
__global__ __launch_bounds__(512, 4) void flash_attn(const u16* __restrict__ Qh, const u16* __restrict__ Kh,
                                                     const u16* __restrict__ VhT, u16* __restrict__ Obuf,
                                                     float* __restrict__ l_ws) {
  __shared__ __align__(16) u16 Ks[2][4096];   // [buf][64 s][8 chunks of 8d], chunk-swizzled
  __shared__ __align__(16) u16 VTs[2][4096];  // [buf][64 d][8 chunks of 8s], chunk-swizzled
  __shared__ __align__(16) u16 Ps[8][1152];   // per wave: [16 t][72 s-padded]
  const int tid = threadIdx.x;
  const int w = tid >> 6, ln = tid & 63, q = ln >> 4, c = ln & 15;
  // XCD swizzle: flat = tx + 16*(h + 16*b) (512 wgs); XCD owns 4 heads' K/V.
  const int lg = xcd_swz(blockIdx.x + 16 * (blockIdx.y + 16 * blockIdx.z), 512);
  const int t0 = (lg & 15) * 128, h = (lg >> 4) & 15, b = lg >> 8;
  const size_t bh = (size_t)(b * 16 + h);
  const u16* Qbase = Qh + bh * 131072;
  const u16* Kbase = Kh + bh * 131072;
  const u16* Vbase = VhT + bh * 131072;

  short8 qf0, qf1;  // B-operand: lane supplies Q[t0+w*16+c][q*8+j (+32)]
  {
    const u16* qr = Qbase + (size_t)(t0 + w * 16 + c) * 64 + q * 8;
    qf0 = *(const short8*)qr;
    qf1 = *(const short8*)(qr + 32);
  }
  floatx4 oacc[4];
  float lacc = 0.f;
#pragma unroll
  for (int j = 0; j < 4; ++j) oacc[j] = (floatx4){0.f, 0.f, 0.f, 0.f};

  const int srow = ln >> 3;
  const int sch = (ln & 7) ^ srow;
  const int cx = c & 7;
  const int row = w * 8 + srow;  // each wave stages 8 rows; lane -> base + ln*16

  // prologue: prefetch s0=0 into buf 0 (each wave: 1 K-load + 1 V-load)
  load16_to_lds((const char*)Kbase + ((size_t)row * 64 + sch * 8) * 2, (char*)Ks[0] + w * 1024);
  load16_to_lds((const char*)Vbase + ((size_t)row * 2048 + sch * 8) * 2, (char*)VTs[0] + w * 1024);

  int cur = 0;
  for (int s0 = 0; s0 < 2048; s0 += 64) {
    __syncthreads();  // drains vmcnt -> buf[cur] staged; all waves done reading buf[cur^1]
    if (s0 + 64 < 2048) {
      const int nb = cur ^ 1;
      load16_to_lds((const char*)Kbase + ((size_t)(s0 + 64 + row) * 64 + sch * 8) * 2,
                    (char*)Ks[nb] + w * 1024);
      load16_to_lds((const char*)Vbase + ((size_t)row * 2048 + (s0 + 64) + sch * 8) * 2,
                    (char*)VTs[nb] + w * 1024);
    }
    const u16* ks = Ks[cur];
    const u16* vs = VTs[cur];
    // QK^T transposed: lane (q,c) gets S'[s=st*16+4q+r][t=c]
#pragma unroll
    for (int st = 0; st < 4; ++st) {
      const int rr = st * 16 + c;
      short8 k0 = *(const short8*)(ks + rr * 64 + ((q ^ cx) << 3));
      short8 k1 = *(const short8*)(ks + rr * 64 + (((4 + q) ^ cx) << 3));
      floatx4 zz = (floatx4){0.f, 0.f, 0.f, 0.f};
      __builtin_amdgcn_s_setprio(1);
      zz = MFMA16(k0, qf0, zz);
      zz = MFMA16(k1, qf1, zz);
      __builtin_amdgcn_s_setprio(0);
      float e0 = EXP2(zz[0]), e1 = EXP2(zz[1]), e2 = EXP2(zz[2]), e3 = EXP2(zz[3]);
      lacc += (e0 + e1) + (e2 + e3);
      uint2v pk = {cvtpk(e0, e1), cvtpk(e2, e3)};
      *(uint2v*)(&Ps[w][c * 72 + st * 16 + 4 * q]) = pk;
    }
    // PV: A = P rows t, B = V^T rows dh
    short8 pf0 = *(const short8*)(&Ps[w][c * 72 + q * 8]);
    short8 pf1 = *(const short8*)(&Ps[w][c * 72 + 32 + q * 8]);
    __builtin_amdgcn_s_setprio(1);
#pragma unroll
    for (int dt = 0; dt < 4; ++dt) {
      const int rr = dt * 16 + c;
      short8 v0 = *(const short8*)(vs + rr * 64 + ((q ^ cx) << 3));
      short8 v1 = *(const short8*)(vs + rr * 64 + (((4 + q) ^ cx) << 3));
      oacc[dt] = MFMA16(pf0, v0, oacc[dt]);
      oacc[dt] = MFMA16(pf1, v1, oacc[dt]);
    }
    __builtin_amdgcn_s_setprio(0);
    cur ^= 1;
  }
  // l reduction: lane holds partial for t=c; sum across the 4 q-groups.
  {
    float v = lacc;
    v += __shfl_xor(v, 16);
    v += __shfl_xor(v, 32);
    lacc = v;
    if (q == 0) l_ws[bh * 2048 + t0 + w * 16 + c] = v;
  }
#pragma unroll
  for (int r = 0; r < 4; ++r) {
    float lv = __shfl(lacc, 4 * q + r);  // lane 4q+r has c==4q+r
    float inv = __builtin_amdgcn_rcpf(lv);
    const int t = t0 + w * 16 + 4 * q + r;
#pragma unroll
    for (int dt = 0; dt < 4; ++dt)
      Obuf[((size_t)b * 2048 + t) * 1024 + h * 64 + dt * 16 + c] = f2bf(oacc[dt][r] * inv);
  }
}

// ---------------------------------------------------------------------------
// K3: attn_avg, S^T form, double-buffered K staging (prefetch-after-barrier,
// one barrier per h), XCD chunk-swizzled. grid (S/64, T/128, B).
__global__ __launch_bounds__(256) void attn_avg_k(const u16* __restrict__ Qh, const u16* __restrict__ Kh,
                                                  const float* __restrict__ l_ws, float* __restrict__ out2) {
  __shared__ __align__(16) u16 Ks[2][4096];
  const int tid = threadIdx.x;
  const int w = tid >> 6, ln = tid & 63, q = ln >> 4, c = ln & 15;
  // XCD swizzle: flat = sx + 32*(ty + 16*b) (1024 wgs); XCD owns 128 contiguous.
  const int lg = xcd_swz(blockIdx.x + 32 * (blockIdx.y + 16 * blockIdx.z), 1024);
  const int s0 = (lg & 31) * 64, t0 = ((lg >> 5) & 15) * 128, b = lg >> 9;
  const int srow = ln >> 3;
  const int sch = (ln & 7) ^ srow;
  const int cx = c & 7;

  floatx4 acc[2][4];  // [blk][st], components = 4 consecutive s (4q+r)
#pragma unroll
  for (int i = 0; i < 2; ++i)
#pragma unroll
    for (int j = 0; j < 4; ++j) acc[i][j] = (floatx4){0.f, 0.f, 0.f, 0.f};

  // prefetch h=0
#pragma unroll
  for (int it = 0; it < 2; ++it) {
    int I = w * 2 + it;
    int row = I * 8 + srow;
    load16_to_lds((const char*)(Kh + (size_t)(b * 16) * 131072) + ((size_t)(s0 + row) * 64 + sch * 8) * 2,
                  (char*)Ks[0] + I * 1024);
  }

  for (int h = 0; h < 16; ++h) {
    const size_t bh = (size_t)(b * 16 + h);
    const u16* ks = Ks[h & 1];
    __syncthreads();  // drains loads for h; all waves done reading buf from h-1
    if (h < 15) {
      const u16* Kn = Kh + (bh + 1) * 131072;
#pragma unroll
      for (int it = 0; it < 2; ++it) {
        int I = w * 2 + it;
        int row = I * 8 + srow;
        load16_to_lds((const char*)Kn + ((size_t)(s0 + row) * 64 + sch * 8) * 2,
                      (char*)Ks[(h + 1) & 1] + I * 1024);
      }
    }
    short8 qf[2][2];
    float linv[2];
#pragma unroll
    for (int blk = 0; blk < 2; ++blk) {
      const u16* qr = Qh + bh * 131072 + (size_t)(t0 + w * 32 + blk * 16 + c) * 64 + q * 8;
      qf[blk][0] = *(const short8*)qr;
      qf[blk][1] = *(const short8*)(qr + 32);
      linv[blk] = __builtin_amdgcn_rcpf(l_ws[bh * 2048 + t0 + w * 32 + blk * 16 + c]) * 0.0625f;
    }
#pragma unroll
    for (int st = 0; st < 4; ++st) {
      const int row = st * 16 + c;
      short8 k0 = *(const short8*)(ks + row * 64 + ((q ^ cx) << 3));
      short8 k1 = *(const short8*)(ks + row * 64 + (((4 + q) ^ cx) << 3));
#pragma unroll
      for (int blk = 0; blk < 2; ++blk) {
        floatx4 zz = (floatx4){0.f, 0.f, 0.f, 0.f};
        zz = MFMA16(k0, qf[blk][0], zz);
        zz = MFMA16(k1, qf[blk][1], zz);
#pragma unroll
        for (int r = 0; r < 4; ++r) acc[blk][st][r] += EXP2(zz[r]) * linv[blk];
      }
    }
  }
#pragma unroll
  for (int blk = 0; blk < 2; ++blk) {
    const size_t t = (size_t)t0 + w * 32 + blk * 16 + c;
#pragma unroll
    for (int st = 0; st < 4; ++st) {
      float4 o;
      o.x = acc[blk][st][0]; o.y = acc[blk][st][1]; o.z = acc[blk][st][2]; o.w = acc[blk][st][3];
      *(float4*)(out2 + ((size_t)b * 2048 + t) * 2048 + s0 + st * 16 + 4 * q) = o;
    }
  }
}

// ---------------------------------------------------------------------------
extern "C" void kernel_launch(void* const* d_in, const int* in_sizes, int n_in,
                              void* d_out, int out_size, void* d_ws, size_t ws_size,
                              hipStream_t stream) {
  const float* query = (const float*)d_in[0];
  const float* key = (const float*)d_in[1];
  const float* value = (const float*)d_in[2];
  const float* Wq = (const float*)d_in[3];
  const float* bq = (const float*)d_in[4];
  const float* Wk = (const float*)d_in[5];
  const float* bk = (const float*)d_in[6];
  const float* Wv = (const float*)d_in[7];
  const float* bv = (const float*)d_in[8];
  const float* Wo = (const float*)d_in[9];
  const float* bo = (const float*)d_in[10];

  char* ws = (char*)d_ws;
  const size_t MB = 1024 * 1024;
  u16* wWq = (u16*)(ws + 0 * MB);
  u16* wWk = (u16*)(ws + 2 * MB);
  u16* wWv = (u16*)(ws + 4 * MB);
  u16* wWo = (u16*)(ws + 6 * MB);
  u16* wQh = (u16*)(ws + 8 * MB);   // [B,H,2048,64] bf16, pre-scaled by QSCALE
  u16* wKh = (u16*)(ws + 16 * MB);  // [B,H,2048,64]
  u16* wVT = (u16*)(ws + 24 * MB);  // [B,H,64,2048]
  u16* wO = (u16*)(ws + 32 * MB);   // [B*T, E] bf16
  float* wl = (float*)(ws + 40 * MB);  // [B,H,T] fp32 row sums
  float* out = (float*)d_out;
  float* out2 = out + (size_t)4194304;

  // bf16 activations stashed in the (not-yet-written) attn_avg output region.
  u16* qb = (u16*)out2;
  u16* kb = qb + 4194304;
  u16* vb = kb + 4194304;

  cvt_all<<<dim3(1024, 16), 256, 0, stream>>>(Wq, Wk, Wv, Wo, query, key, value,
                                              wWq, wWk, wWv, wWo, qb, kb, vb);
  qkv_gemm<<<dim3(8, 16, 3), 512, 0, stream>>>(qb, kb, vb, wWq, wWk, wWv,
                                               bq, bk, bv, wQh, wKh, wVT);
  flash_attn<<<dim3(16, 16, 2), 512, 0, stream>>>(wQh, wKh, wVT, wO, wl);
  attn_avg_k<<<dim3(32, 16, 2), 256, 0, stream>>>(wQh, wKh, wl, out2);
  oproj_gemm<<<dim3(8, 16), 512, 0, stream>>>(wO, wWo, bo, out);
}

// Round 6
// 266.351 us; speedup vs baseline: 1.0522x; 1.0522x over previous
//
#include <hip/hip_runtime.h>

#define DEV __device__ __forceinline__

typedef __attribute__((ext_vector_type(8))) short short8;
typedef __attribute__((ext_vector_type(4))) float floatx4;
typedef __attribute__((ext_vector_type(2))) unsigned int uint2v;
typedef unsigned short u16;

// round-to-nearest-even fp32 -> bf16 (bit pattern)
DEV u16 f2bf(float f) {
  unsigned int u = __float_as_uint(f);
  u += 0x7fffu + ((u >> 16) & 1u);
  return (u16)(u >> 16);
}

// pack two fp32 -> 2 bf16 in one u32 (a -> lo, b -> hi), single instruction, RNE
DEV unsigned int cvtpk(float a, float b) {
  unsigned int r;
  asm("v_cvt_pk_bf16_f32 %0, %1, %2" : "=v"(r) : "v"(a), "v"(b));
  return r;
}

// async global->LDS, 16B/lane; LDS dest = wave-uniform base + lane*16
DEV void load16_to_lds(const void* g, void* l) {
  __builtin_amdgcn_global_load_lds(
      (const __attribute__((address_space(1))) unsigned int*)g,
      (__attribute__((address_space(3))) unsigned int*)l, 16, 0, 0);
}

// XCD chunk-swizzle (T1). Requires nwg % 8 == 0 (bijective).
DEV int xcd_swz(int flat, int nwg) {
  return (flat & 7) * (nwg >> 3) + (flat >> 3);
}

#define MFMA16(A, B, C) __builtin_amdgcn_mfma_f32_16x16x32_bf16(A, B, C, 0, 0, 0)
#define EXP2(x) __builtin_amdgcn_exp2f(x)  // raw v_exp_f32; args bounded ~|12|

// Problem constants: B=2, T=S=2048, E=1024, H=16, DH=64
// Q pre-scale: (1/8) * log2(e) so softmax uses exp2 directly.
#define QSCALE 0.18033688011112042f

// ---------------------------------------------------------------------------
// Swizzled 16-row x 32-k LDS blocks (1 KB). Global chunk g (16B) of row r
// lives at slot r*4 + ((g + (r>>2)) & 3). 2-way residue -> conflict-free.
DEV void stage_block(const u16* src_row0, int k0, int ln, void* ldsbase) {
  int r = ln >> 2;
  int p = ((ln & 3) - (ln >> 4)) & 3;
  load16_to_lds((const char*)(src_row0 + (size_t)r * 1024 + k0) + p * 16, ldsbase);
}
DEV const short8* frag_addr(const u16* base, int blk, int c, int q) {
  int slot = c * 4 + ((q + (c >> 2)) & 3);
  return (const short8*)(base + blk * 512 + slot * 8);
}

// ---------------------------------------------------------------------------
// K0: fp32->bf16 of 4 weight matrices (1M el each) + 3 activations (4M el each)
__global__ __launch_bounds__(256) void cvt_all(
    const float* __restrict__ w0, const float* __restrict__ w1,
    const float* __restrict__ w2, const float* __restrict__ w3,
    const float* __restrict__ a0, const float* __restrict__ a1, const float* __restrict__ a2,
    u16* __restrict__ e0, u16* __restrict__ e1, u16* __restrict__ e2, u16* __restrict__ e3,
    u16* __restrict__ f0, u16* __restrict__ f1, u16* __restrict__ f2) {
  const int t = blockIdx.y;
  const float* s;
  u16* d;
  size_t base;
  if (t < 4) {
    s = t == 0 ? w0 : t == 1 ? w1 : t == 2 ? w2 : w3;
    d = t == 0 ? e0 : t == 1 ? e1 : t == 2 ? e2 : e3;
    base = 0;
  } else {
    int a = (t - 4) >> 2;
    s = a == 0 ? a0 : a == 1 ? a1 : a2;
    d = a == 0 ? f0 : a == 1 ? f1 : f2;
    base = (size_t)((t - 4) & 3) * 1048576;
  }
  size_t i = base + (size_t)(blockIdx.x * 256 + threadIdx.x) * 4;
  float4 v = *(const float4*)(s + i);
  ushort4 o;
  o.x = f2bf(v.x); o.y = f2bf(v.y); o.z = f2bf(v.z); o.w = f2bf(v.w);
  *(ushort4*)(d + i) = o;
}

// ---------------------------------------------------------------------------
// QKV projection GEMM, pure bf16, 256x128 tile, BK=32, 8 waves (4x2 of 64x64).
// Double-buffered LDS, one barrier per K-step. grid (8, 16, 3): bx is the
// n-panel for z<=1 -> natural %8 XCD round-robin pins one 0.25MB B-panel per
// XCD (L2-resident) while the A-stream walks m sequentially.
__global__ __launch_bounds__(512, 4) void qkv_gemm(
    const u16* __restrict__ qb, const u16* __restrict__ kb, const u16* __restrict__ vb,
    const u16* __restrict__ wq, const u16* __restrict__ wk, const u16* __restrict__ wv,
    const float* __restrict__ bq, const float* __restrict__ bk, const float* __restrict__ bv,
    u16* __restrict__ Qh, u16* __restrict__ Kh, u16* __restrict__ VT) {
  __shared__ __align__(16) u16 As[2][8192];  // 16 x 1KB row-blocks
  __shared__ __align__(16) u16 Bs[2][4096];  // 8 x 1KB row-blocks
  const int tid = threadIdx.x;
  const int w = tid >> 6, ln = tid & 63, q = ln >> 4, c = ln & 15;
  const int wr = w >> 1, wc = w & 1;  // 4x2 wave grid, 64x64 each
  const int z = blockIdx.z;
  int m_idx, n_idx;
  if (z == 2) {  // A=wv (M=1024), B=vb (N=4096)
    int f2 = blockIdx.x + 8 * blockIdx.y;  // 0..127
    n_idx = f2 & 31;
    m_idx = f2 >> 5;
  } else {  // A=activations (M=4096), B=weights (N=1024)
    n_idx = blockIdx.x;
    m_idx = blockIdx.y;
  }
  const int m0 = m_idx * 256, n0 = n_idx * 128;
  const u16* Asrc = z == 0 ? qb : (z == 1 ? kb : wv);
  const u16* Bsrc = z == 0 ? wq : (z == 1 ? wk : vb);

  floatx4 acc[4][4];
#pragma unroll
  for (int i = 0; i < 4; ++i)
#pragma unroll
    for (int j = 0; j < 4; ++j) acc[i][j] = (floatx4){0.f, 0.f, 0.f, 0.f};

  // 24 x 1KB stage blocks per K-step (A:16, B:8); wave w does idx = w*3+j.
#pragma unroll
  for (int j = 0; j < 3; ++j) {
    int idx = w * 3 + j;
    if (idx < 16)
      stage_block(Asrc + (size_t)(m0 + idx * 16) * 1024, 0, ln, (char*)As[0] + idx * 1024);
    else
      stage_block(Bsrc + (size_t)(n0 + (idx - 16) * 16) * 1024, 0, ln, (char*)Bs[0] + (idx - 16) * 1024);
  }

  int cur = 0;
  for (int k0 = 0; k0 < 1024; k0 += 32) {
    __syncthreads();  // drains vmcnt -> buf[cur] staged; all waves done reading buf[cur^1]
    if (k0 + 32 < 1024) {
      const int nb = cur ^ 1;
#pragma unroll
      for (int j = 0; j < 3; ++j) {
        int idx = w * 3 + j;
        if (idx < 16)
          stage_block(Asrc + (size_t)(m0 + idx * 16) * 1024, k0 + 32, ln, (char*)As[nb] + idx * 1024);
        else
          stage_block(Bsrc + (size_t)(n0 + (idx - 16) * 16) * 1024, k0 + 32, ln,
                      (char*)Bs[nb] + (idx - 16) * 1024);
      }
    }
    short8 a[4], bb[4];
#pragma unroll
    for (int mt = 0; mt < 4; ++mt) a[mt] = *frag_addr(As[cur], wr * 4 + mt, c, q);
#pragma unroll
    for (int nt = 0; nt < 4; ++nt) bb[nt] = *frag_addr(Bs[cur], wc * 4 + nt, c, q);
    __builtin_amdgcn_s_setprio(1);
#pragma unroll
    for (int mt = 0; mt < 4; ++mt)
#pragma unroll
      for (int nt = 0; nt < 4; ++nt) acc[mt][nt] = MFMA16(a[mt], bb[nt], acc[mt][nt]);
    __builtin_amdgcn_s_setprio(0);
    cur ^= 1;
  }

  if (z <= 1) {
    const float* bias = z ? bk : bq;
    u16* dst = z ? Kh : Qh;
    const float scale = z ? 1.0f : QSCALE;
    float bn[4];
#pragma unroll
    for (int nt = 0; nt < 4; ++nt) bn[nt] = bias[n0 + wc * 64 + nt * 16 + c];
#pragma unroll
    for (int mt = 0; mt < 4; ++mt)
#pragma unroll
      for (int r = 0; r < 4; ++r) {
        int m = m0 + wr * 64 + mt * 16 + 4 * q + r;
        int bbv = m >> 11, t = m & 2047;
#pragma unroll
        for (int nt = 0; nt < 4; ++nt) {
          int n = n0 + wc * 64 + nt * 16 + c;
          dst[((size_t)(bbv * 16 + (n >> 6)) * 2048 + t) * 64 + (n & 63)] =
              f2bf((acc[mt][nt][r] + bn[nt]) * scale);
        }
      }
  } else {
    float bm[4][4];
#pragma unroll
    for (int mt = 0; mt < 4; ++mt)
#pragma unroll
      for (int r = 0; r < 4; ++r) bm[mt][r] = bv[m0 + wr * 64 + mt * 16 + 4 * q + r];
#pragma unroll
    for (int mt = 0; mt < 4; ++mt)
#pragma unroll
      for (int r = 0; r < 4; ++r) {
        int d = m0 + wr * 64 + mt * 16 + 4 * q + r;
        int hh = d >> 6, dl = d & 63;
#pragma unroll
        for (int nt = 0; nt < 4; ++nt) {
          int s = n0 + wc * 64 + nt * 16 + c;
          int bbv = s >> 11, sl = s & 2047;
          VT[((size_t)(bbv * 16 + hh) * 64 + dl) * 2048 + sl] = f2bf(acc[mt][nt][r] + bm[mt][r]);
        }
      }
  }
}

// ---------------------------------------------------------------------------
// Output projection: out[4096,1024] = A_bf16 @ Wo^T + bo (fp32). 128x128 tile,
// 256 threads (2x2 waves of 64x64), double-buffered. grid (8, 32) = 256 wg ->
// one per CU; natural %8 pins one 256KB Wo n-panel per XCD.
__global__ __launch_bounds__(256) void oproj_gemm(const u16* __restrict__ Ap, const u16* __restrict__ Wp,
                                                  const float* __restrict__ bias, float* __restrict__ out) {
  __shared__ __align__(16) u16 As[2][4096];
  __shared__ __align__(16) u16 Bs[2][4096];
  const int tid = threadIdx.x;
  const int w = tid >> 6, ln = tid & 63, q = ln >> 4, c = ln & 15;
  const int wr = w >> 1, wc = w & 1;
  const int n0 = blockIdx.x * 128, m0 = blockIdx.y * 128;

  floatx4 acc[4][4];
#pragma unroll
  for (int i = 0; i < 4; ++i)
#pragma unroll
    for (int j = 0; j < 4; ++j) acc[i][j] = (floatx4){0.f, 0.f, 0.f, 0.f};

#pragma unroll
  for (int it = 0; it < 2; ++it) {
    int I = w * 2 + it;
    stage_block(Ap + (size_t)(m0 + I * 16) * 1024, 0, ln, (char*)As[0] + I * 1024);
    stage_block(Wp + (size_t)(n0 + I * 16) * 1024, 0, ln, (char*)Bs[0] + I * 1024);
  }

  int cur = 0;
  for (int k0 = 0; k0 < 1024; k0 += 32) {
    __syncthreads();
    if (k0 + 32 < 1024) {
      const int nb = cur ^ 1;
#pragma unroll
      for (int it = 0; it < 2; ++it) {
        int I = w * 2 + it;
        stage_block(Ap + (size_t)(m0 + I * 16) * 1024, k0 + 32, ln, (char*)As[nb] + I * 1024);
        stage_block(Wp + (size_t)(n0 + I * 16) * 1024, k0 + 32, ln, (char*)Bs[nb] + I * 1024);
      }
    }
    short8 a[4], bb[4];
#pragma unroll
    for (int mt = 0; mt < 4; ++mt) a[mt] = *frag_addr(As[cur], wr * 4 + mt, c, q);
#pragma unroll
    for (int nt = 0; nt < 4; ++nt) bb[nt] = *frag_addr(Bs[cur], wc * 4 + nt, c, q);
    __builtin_amdgcn_s_setprio(1);
#pragma unroll
    for (int mt = 0; mt < 4; ++mt)
#pragma unroll
      for (int nt = 0; nt < 4; ++nt) acc[mt][nt] = MFMA16(a[mt], bb[nt], acc[mt][nt]);
    __builtin_amdgcn_s_setprio(0);
    cur ^= 1;
  }

  float bn[4];
#pragma unroll
  for (int nt = 0; nt < 4; ++nt) bn[nt] = bias[n0 + wc * 64 + nt * 16 + c];
#pragma unroll
  for (int mt = 0; mt < 4; ++mt)
#pragma unroll
    for (int r = 0; r < 4; ++r) {
      int m = m0 + wr * 64 + mt * 16 + 4 * q + r;
#pragma unroll
      for (int nt = 0; nt < 4; ++nt)
        out[(size_t)m * 1024 + n0 + wc * 64 + nt * 16 + c] = acc[mt][nt][r] + bn[nt];
    }
}

// ---------------------------------------------------------------------------
// K2: flash attention, S^T form, t-tile 128 (16 t per wave, 8 waves).
// Software-pipelined: per s-tile i, issue QK(i) MFMA, then PV(i-1) MFMA, then
// softmax(i) VALU -> PV MFMAs overlap softmax's exp2/cvtpk instead of
// alternating in barrier lockstep. V triple-buffered (PV reads tile i-1 while
// prefetch writes tile i+1); per-wave P scratch double-buffered.
// grid (T/128, H, B) = (16,16,2), 512 threads. LDS 76 KB -> 2 blocks/CU.
__global__ __launch_bounds__(512, 4) void flash_attn(const u16* __restrict__ Qh, const u16* __restrict__ Kh,
                                                     const u16* __restrict__ VhT, u16* __restrict__ Obuf,
                                                     float* __restrict__ l_ws) {
  __shared__ __align__(16) u16 Ks[2][4096];     // [buf][64 s][8 chunks of 8d], chunk-swizzled
  __shared__ __align__(16) u16 VTs[3][4096];    // [buf][64 d][8 chunks of 8s], chunk-swizzled
  __shared__ __align__(16) u16 Ps[8][2][1152];  // per wave, dbuf: [16 t][72 s-padded]
  const int tid = threadIdx.x;
  const int w = tid >> 6, ln = tid & 63, q = ln >> 4, c = ln & 15;
  // XCD swizzle: flat = tx + 16*(h + 16*b) (512 wgs); XCD owns 4 heads' K/V.
  const int lg = xcd_swz(blockIdx.x + 16 * (blockIdx.y + 16 * blockIdx.z), 512);
  const int t0 = (lg & 15) * 128, h = (lg >> 4) & 15, b = lg >> 8;
  const size_t bh = (size_t)(b * 16 + h);
  const u16* Qbase = Qh + bh * 131072;
  const u16* Kbase = Kh + bh * 131072;
  const u16* Vbase = VhT + bh * 131072;

  short8 qf0, qf1;  // B-operand: lane supplies Q[t0+w*16+c][q*8+j (+32)]
  {
    const u16* qr = Qbase + (size_t)(t0 + w * 16 + c) * 64 + q * 8;
    qf0 = *(const short8*)qr;
    qf1 = *(const short8*)(qr + 32);
  }
  floatx4 oacc[4];
  float lacc = 0.f;
#pragma unroll
  for (int j = 0; j < 4; ++j) oacc[j] = (floatx4){0.f, 0.f, 0.f, 0.f};

  const int srow = ln >> 3;
  const int sch = (ln & 7) ^ srow;
  const int cx = c & 7;
  const int row = w * 8 + srow;  // each wave stages 8 rows; lane -> base + ln*16

  // prologue: stage tile 0 into K[0]/V[0] (each wave: 1 K-load + 1 V-load)
  load16_to_lds((const char*)Kbase + ((size_t)row * 64 + sch * 8) * 2, (char*)Ks[0] + w * 1024);
  load16_to_lds((const char*)Vbase + ((size_t)row * 2048 + sch * 8) * 2, (char*)VTs[0] + w * 1024);

  int vc = 0;  // V buffer of tile i (== i % 3)
  for (int i = 0; i < 32; ++i) {
    const int s0 = i * 64;
    __syncthreads();  // drains vmcnt/lgkmcnt -> tile i staged; prior reads done
    int vn = vc + 1;
    if (vn == 3) vn = 0;
    int vp = vc - 1;
    if (vp < 0) vp = 2;
    if (i + 1 < 32) {
      load16_to_lds((const char*)Kbase + ((size_t)(s0 + 64 + row) * 64 + sch * 8) * 2,
                    (char*)Ks[(i + 1) & 1] + w * 1024);
      load16_to_lds((const char*)Vbase + ((size_t)row * 2048 + (s0 + 64) + sch * 8) * 2,
                    (char*)VTs[vn] + w * 1024);
    }
    const u16* ks = Ks[i & 1];
    // QK(i): lane (q,c) gets S'[s=st*16+4q+r][t=c]
    floatx4 zz[4];
    __builtin_amdgcn_s_setprio(1);
#pragma unroll
    for (int st = 0; st < 4; ++st) {
      const int rr = st * 16 + c;
      short8 k0 = *(const short8*)(ks + rr * 64 + ((q ^ cx) << 3));
      short8 k1 = *(const short8*)(ks + rr * 64 + (((4 + q) ^ cx) << 3));
      zz[st] = (floatx4){0.f, 0.f, 0.f, 0.f};
      zz[st] = MFMA16(k0, qf0, zz[st]);
      zz[st] = MFMA16(k1, qf1, zz[st]);
    }
    __builtin_amdgcn_s_setprio(0);
    // PV(i-1): independent of softmax(i) -> MFMA pipe overlaps VALU below
    if (i > 0) {
      const u16* vs = VTs[vp];
      const u16* pw = Ps[w][(i - 1) & 1];
      short8 pf0 = *(const short8*)(pw + c * 72 + q * 8);
      short8 pf1 = *(const short8*)(pw + c * 72 + 32 + q * 8);
      __builtin_amdgcn_s_setprio(1);
#pragma unroll
      for (int dt = 0; dt < 4; ++dt) {
        const int rr = dt * 16 + c;
        short8 v0 = *(const short8*)(vs + rr * 64 + ((q ^ cx) << 3));
        short8 v1 = *(const short8*)(vs + rr * 64 + (((4 + q) ^ cx) << 3));
        oacc[dt] = MFMA16(pf0, v0, oacc[dt]);
        oacc[dt] = MFMA16(pf1, v1, oacc[dt]);
      }
      __builtin_amdgcn_s_setprio(0);
    }
    // softmax(i) -> Ps[w][i&1]
    u16* pwr = Ps[w][i & 1];
#pragma unroll
    for (int st = 0; st < 4; ++st) {
      float e0 = EXP2(zz[st][0]), e1 = EXP2(zz[st][1]), e2 = EXP2(zz[st][2]), e3 = EXP2(zz[st][3]);
      lacc += (e0 + e1) + (e2 + e3);
      uint2v pk = {cvtpk(e0, e1), cvtpk(e2, e3)};
      *(uint2v*)(pwr + c * 72 + st * 16 + 4 * q) = pk;
    }
    vc = vn;
  }
  // epilogue: PV(31). Tile 31 V is in VTs[31%3=1]; P in Ps[w][31&1=1].
  {
    const u16* vs = VTs[1];
    const u16* pw = Ps[w][1];
    short8 pf0 = *(const short8*)(pw + c * 72 + q * 8);
    short8 pf1 = *(const short8*)(pw + c * 72 + 32 + q * 8);
#pragma unroll
    for (int dt = 0; dt < 4; ++dt) {
      const int rr = dt * 16 + c;
      short8 v0 = *(const short8*)(vs + rr * 64 + ((q ^ cx) << 3));
      short8 v1 = *(const short8*)(vs + rr * 64 + (((4 + q) ^ cx) << 3));
      oacc[dt] = MFMA16(pf0, v0, oacc[dt]);
      oacc[dt] = MFMA16(pf1, v1, oacc[dt]);
    }
  }
  // l reduction: lane holds partial for t=c; sum across the 4 q-groups.
  {
    float v = lacc;
    v += __shfl_xor(v, 16);
    v += __shfl_xor(v, 32);
    lacc = v;
    if (q == 0) l_ws[bh * 2048 + t0 + w * 16 + c] = v;
  }
#pragma unroll
  for (int r = 0; r < 4; ++r) {
    float lv = __shfl(lacc, 4 * q + r);  // lane 4q+r has c==4q+r
    float inv = __builtin_amdgcn_rcpf(lv);
    const int t = t0 + w * 16 + 4 * q + r;
#pragma unroll
    for (int dt = 0; dt < 4; ++dt)
      Obuf[((size_t)b * 2048 + t) * 1024 + h * 64 + dt * 16 + c] = f2bf(oacc[dt][r] * inv);
  }
}

// ---------------------------------------------------------------------------
// K3: attn_avg, S^T form, double-buffered K staging (prefetch-after-barrier,
// one barrier per h), XCD chunk-swizzled. grid (S/64, T/128, B).
__global__ __launch_bounds__(256) void attn_avg_k(const u16* __restrict__ Qh, const u16* __restrict__ Kh,
                                                  const float* __restrict__ l_ws, float* __restrict__ out2) {
  __shared__ __align__(16) u16 Ks[2][4096];
  const int tid = threadIdx.x;
  const int w = tid >> 6, ln = tid & 63, q = ln >> 4, c = ln & 15;
  // XCD swizzle: flat = sx + 32*(ty + 16*b) (1024 wgs); XCD owns 128 contiguous.
  const int lg = xcd_swz(blockIdx.x + 32 * (blockIdx.y + 16 * blockIdx.z), 1024);
  const int s0 = (lg & 31) * 64, t0 = ((lg >> 5) & 15) * 128, b = lg >> 9;
  const int srow = ln >> 3;
  const int sch = (ln & 7) ^ srow;
  const int cx = c & 7;

  floatx4 acc[2][4];  // [blk][st], components = 4 consecutive s (4q+r)
#pragma unroll
  for (int i = 0; i < 2; ++i)
#pragma unroll
    for (int j = 0; j < 4; ++j) acc[i][j] = (floatx4){0.f, 0.f, 0.f, 0.f};

  // prefetch h=0
#pragma unroll
  for (int it = 0; it < 2; ++it) {
    int I = w * 2 + it;
    int row = I * 8 + srow;
    load16_to_lds((const char*)(Kh + (size_t)(b * 16) * 131072) + ((size_t)(s0 + row) * 64 + sch * 8) * 2,
                  (char*)Ks[0] + I * 1024);
  }

  for (int h = 0; h < 16; ++h) {
    const size_t bh = (size_t)(b * 16 + h);
    const u16* ks = Ks[h & 1];
    __syncthreads();  // drains loads for h; all waves done reading buf from h-1
    if (h < 15) {
      const u16* Kn = Kh + (bh + 1) * 131072;
#pragma unroll
      for (int it = 0; it < 2; ++it) {
        int I = w * 2 + it;
        int row = I * 8 + srow;
        load16_to_lds((const char*)Kn + ((size_t)(s0 + row) * 64 + sch * 8) * 2,
                      (char*)Ks[(h + 1) & 1] + I * 1024);
      }
    }
    short8 qf[2][2];
    float linv[2];
#pragma unroll
    for (int blk = 0; blk < 2; ++blk) {
      const u16* qr = Qh + bh * 131072 + (size_t)(t0 + w * 32 + blk * 16 + c) * 64 + q * 8;
      qf[blk][0] = *(const short8*)qr;
      qf[blk][1] = *(const short8*)(qr + 32);
      linv[blk] = __builtin_amdgcn_rcpf(l_ws[bh * 2048 + t0 + w * 32 + blk * 16 + c]) * 0.0625f;
    }
#pragma unroll
    for (int st = 0; st < 4; ++st) {
      const int row = st * 16 + c;
      short8 k0 = *(const short8*)(ks + row * 64 + ((q ^ cx) << 3));
      short8 k1 = *(const short8*)(ks + row * 64 + (((4 + q) ^ cx) << 3));
#pragma unroll
      for (int blk = 0; blk < 2; ++blk) {
        floatx4 zz = (floatx4){0.f, 0.f, 0.f, 0.f};
        zz = MFMA16(k0, qf[blk][0], zz);
        zz = MFMA16(k1, qf[blk][1], zz);
#pragma unroll
        for (int r = 0; r < 4; ++r) acc[blk][st][r] += EXP2(zz[r]) * linv[blk];
      }
    }
  }
#pragma unroll
  for (int blk = 0; blk < 2; ++blk) {
    const size_t t = (size_t)t0 + w * 32 + blk * 16 + c;
#pragma unroll
    for (int st = 0; st < 4; ++st) {
      float4 o;
      o.x = acc[blk][st][0]; o.y = acc[blk][st][1]; o.z = acc[blk][st][2]; o.w = acc[blk][st][3];
      *(float4*)(out2 + ((size_t)b * 2048 + t) * 2048 + s0 + st * 16 + 4 * q) = o;
    }
  }
}

// ---------------------------------------------------------------------------
extern "C" void kernel_launch(void* const* d_in, const int* in_sizes, int n_in,
                              void* d_out, int out_size, void* d_ws, size_t ws_size,
                              hipStream_t stream) {
  const float* query = (const float*)d_in[0];
  const float* key = (const float*)d_in[1];
  const float* value = (const float*)d_in[2];
  const float* Wq = (const float*)d_in[3];
  const float* bq = (const float*)d_in[4];
  const float* Wk = (const float*)d_in[5];
  const float* bk = (const float*)d_in[6];
  const float* Wv = (const float*)d_in[7];
  const float* bv = (const float*)d_in[8];
  const float* Wo = (const float*)d_in[9];
  const float* bo = (const float*)d_in[10];

  char* ws = (char*)d_ws;
  const size_t MB = 1024 * 1024;
  u16* wWq = (u16*)(ws + 0 * MB);
  u16* wWk = (u16*)(ws + 2 * MB);
  u16* wWv = (u16*)(ws + 4 * MB);
  u16* wWo = (u16*)(ws + 6 * MB);
  u16* wQh = (u16*)(ws + 8 * MB);   // [B,H,2048,64] bf16, pre-scaled by QSCALE
  u16* wKh = (u16*)(ws + 16 * MB);  // [B,H,2048,64]
  u16* wVT = (u16*)(ws + 24 * MB);  // [B,H,64,2048]
  u16* wO = (u16*)(ws + 32 * MB);   // [B*T, E] bf16
  float* wl = (float*)(ws + 40 * MB);  // [B,H,T] fp32 row sums
  float* out = (float*)d_out;
  float* out2 = out + (size_t)4194304;

  // bf16 activations stashed in the (not-yet-written) attn_avg output region.
  u16* qb = (u16*)out2;
  u16* kb = qb + 4194304;
  u16* vb = kb + 4194304;

  cvt_all<<<dim3(1024, 16), 256, 0, stream>>>(Wq, Wk, Wv, Wo, query, key, value,
                                              wWq, wWk, wWv, wWo, qb, kb, vb);
  qkv_gemm<<<dim3(8, 16, 3), 512, 0, stream>>>(qb, kb, vb, wWq, wWk, wWv,
                                               bq, bk, bv, wQh, wKh, wVT);
  flash_attn<<<dim3(16, 16, 2), 512, 0, stream>>>(wQh, wKh, wVT, wO, wl);
  attn_avg_k<<<dim3(32, 16, 2), 256, 0, stream>>>(wQh, wKh, wl, out2);
  oproj_gemm<<<dim3(8, 32), 256, 0, stream>>>(wO, wWo, bo, out);
}